// Round 1
// baseline (1110.332 us; speedup 1.0000x reference)
//
#include <hip/hip_runtime.h>
#include <hip/hip_bf16.h>

// Pipeline:
//  x (4,64,130,130) --conv3x3 valid + bias + maxpool2x2--> p1 (4,64,64,64)
//  p1 --1x1 conv (64->32)--> t2 (4,32,64,64)
//  t2 --3x3 conv pad=1 (32->32)--> t3 (4,32,64,64)
//  t3 --1x1 conv (32->1152)--> t4 (4,1152,64,64)   [offset field at half res]
//  deform_conv(x, upsample2x(t4), wd) -> out (4,64,128,128)
//  (upsample fused into deform kernel: read t4 at (ho>>1, wo>>1))

#define HX 130
#define WX 130

// ---------------- K0: transpose wd (o,c,9) -> (c,o,9) for contiguous scalar loads
__global__ __launch_bounds__(256) void k_wdt(const float* __restrict__ wd,
                                             float* __restrict__ wdt) {
    int idx = blockIdx.x * 256 + threadIdx.x;   // 64*64*9 = 36864
    if (idx >= 36864) return;
    int k = idx % 9;
    int rem = idx / 9;
    int c = rem & 63;
    int o = rem >> 6;
    wdt[(c * 64 + o) * 9 + k] = wd[idx];
}

// ---------------- K1: conv3x3 valid (64->64) + bias + maxpool 2x2 -> p1
// grid: 4096 blocks = b(4) * co(64) * tile(16), block 256 = 4 pooled rows x 64 cols
__global__ __launch_bounds__(256) void k_conv0_pool(const float* __restrict__ x,
                                                    const float* __restrict__ w0,
                                                    const float* __restrict__ b0,
                                                    float* __restrict__ p1) {
    int blk = blockIdx.x;
    int tile = blk & 15;
    int co = (blk >> 4) & 63;
    int b = blk >> 10;
    int tid = threadIdx.x;
    int pw = tid & 63;
    int phl = tid >> 6;           // 0..3
    int ph = tile * 4 + phl;
    __shared__ float slab[10 * WX];
    const float* xb = x + (size_t)(b * 64) * HX * WX;
    int row0 = tile * 8;          // x rows row0..row0+9 cover this tile
    float acc0 = 0.f, acc1 = 0.f, acc2 = 0.f, acc3 = 0.f;
    for (int ci = 0; ci < 64; ++ci) {
        __syncthreads();
        const float* xp = xb + (size_t)ci * HX * WX + row0 * WX;
        for (int i = tid; i < 10 * WX; i += 256) slab[i] = xp[i];
        __syncthreads();
        const float* wp = w0 + ((co * 64) + ci) * 9;
        float w[9];
        #pragma unroll
        for (int k = 0; k < 9; ++k) w[k] = wp[k];
        float v[4][4];
        #pragma unroll
        for (int r = 0; r < 4; ++r)
            #pragma unroll
            for (int cc = 0; cc < 4; ++cc)
                v[r][cc] = slab[(2 * phl + r) * WX + 2 * pw + cc];
        #pragma unroll
        for (int dr = 0; dr < 2; ++dr) {
            #pragma unroll
            for (int dc = 0; dc < 2; ++dc) {
                float s = 0.f;
                #pragma unroll
                for (int ky = 0; ky < 3; ++ky)
                    #pragma unroll
                    for (int kx = 0; kx < 3; ++kx)
                        s += w[ky * 3 + kx] * v[dr + ky][dc + kx];
                if (dr == 0 && dc == 0) acc0 += s;
                else if (dr == 0) acc1 += s;
                else if (dc == 0) acc2 += s;
                else acc3 += s;
            }
        }
    }
    float m = fmaxf(fmaxf(acc0, acc1), fmaxf(acc2, acc3)) + b0[co];
    p1[(((size_t)b * 64 + co) * 64 + ph) * 64 + pw] = m;
}

// ---------------- K2: 1x1 conv 64->32 on 64x64
// thread per (b, cog of 8 outputs, pixel): 4*4*4096 = 65536 threads
__global__ __launch_bounds__(256) void k_conv1x1_a(const float* __restrict__ p1,
                                                   const float* __restrict__ w1,
                                                   const float* __restrict__ b1,
                                                   float* __restrict__ t2) {
    int idx = blockIdx.x * 256 + threadIdx.x;
    int p = idx & 4095;
    int cog = (idx >> 12) & 3;
    int b = idx >> 14;
    float acc[8];
    #pragma unroll
    for (int i = 0; i < 8; ++i) acc[i] = b1[cog * 8 + i];
    const float* ip = p1 + (size_t)b * 64 * 4096 + p;
    for (int ci = 0; ci < 64; ++ci) {
        float v = ip[(size_t)ci * 4096];
        #pragma unroll
        for (int i = 0; i < 8; ++i) acc[i] += w1[(cog * 8 + i) * 64 + ci] * v;
    }
    float* op = t2 + (size_t)b * 32 * 4096 + p;
    #pragma unroll
    for (int i = 0; i < 8; ++i) op[(size_t)(cog * 8 + i) * 4096] = acc[i];
}

// ---------------- K3: 3x3 conv pad=1, 32->32 on 64x64
// thread per (b, cog of 8, pixel): 65536 threads
__global__ __launch_bounds__(256) void k_conv3x3_b(const float* __restrict__ t2,
                                                   const float* __restrict__ w2,
                                                   const float* __restrict__ b2,
                                                   float* __restrict__ t3) {
    int idx = blockIdx.x * 256 + threadIdx.x;
    int p = idx & 4095;
    int cog = (idx >> 12) & 3;
    int b = idx >> 14;
    int hy = p >> 6, wx = p & 63;
    float acc[8];
    #pragma unroll
    for (int i = 0; i < 8; ++i) acc[i] = b2[cog * 8 + i];
    const float* ip = t2 + (size_t)b * 32 * 4096;
    for (int ci = 0; ci < 32; ++ci) {
        float v[9];
        #pragma unroll
        for (int ky = 0; ky < 3; ++ky) {
            int yy = hy + ky - 1;
            #pragma unroll
            for (int kx = 0; kx < 3; ++kx) {
                int xx = wx + kx - 1;
                bool ok = (yy >= 0 && yy < 64 && xx >= 0 && xx < 64);
                int yc = min(max(yy, 0), 63), xc = min(max(xx, 0), 63);
                float val = ip[(size_t)ci * 4096 + yc * 64 + xc];
                v[ky * 3 + kx] = ok ? val : 0.f;
            }
        }
        #pragma unroll
        for (int i = 0; i < 8; ++i) {
            const float* wp = w2 + (((cog * 8 + i) * 32) + ci) * 9;
            float s = acc[i];
            #pragma unroll
            for (int k = 0; k < 9; ++k) s += wp[k] * v[k];
            acc[i] = s;
        }
    }
    float* op = t3 + (size_t)b * 32 * 4096 + p;
    #pragma unroll
    for (int i = 0; i < 8; ++i) op[(size_t)(cog * 8 + i) * 4096] = acc[i];
}

// ---------------- K4: 1x1 conv 32->1152 on 64x64 -> offset field t4
// thread per (b, chg of 64 out-channels (18 groups), pixel): 294912 threads
__global__ __launch_bounds__(256) void k_conv1x1_off(const float* __restrict__ t3,
                                                     const float* __restrict__ w3,
                                                     const float* __restrict__ b3,
                                                     float* __restrict__ t4) {
    int idx = blockIdx.x * 256 + threadIdx.x;   // 4*18*4096
    int p = idx & 4095;
    int g = idx >> 12;          // b*18 + chg
    int chg = g % 18;
    int b = g / 18;
    float v[32];
    const float* ip = t3 + (size_t)b * 32 * 4096 + p;
    #pragma unroll
    for (int ci = 0; ci < 32; ++ci) v[ci] = ip[(size_t)ci * 4096];
    float* op = t4 + (size_t)b * 1152 * 4096 + p;
    for (int j = 0; j < 64; ++j) {
        int ch = chg * 64 + j;
        float acc = b3[ch];
        const float* wp = w3 + ch * 32;
        #pragma unroll
        for (int ci = 0; ci < 32; ++ci) acc += wp[ci] * v[ci];
        op[(size_t)ch * 4096] = acc;
    }
}

// ---------------- K5: deformable conv (fused 2x upsample of offsets)
// thread per (b, half of Cout, ho, wo): 4*2*128*128 = 131072 threads, acc[32]
__global__ __launch_bounds__(256) void k_deform(const float* __restrict__ x,
                                                const float* __restrict__ t4,
                                                const float* __restrict__ wdt,
                                                float* __restrict__ out) {
    int idx = blockIdx.x * 256 + threadIdx.x;
    int wo = idx & 127;
    int ho = (idx >> 7) & 127;
    int half = (idx >> 14) & 1;
    int b = idx >> 15;
    int po = ((ho >> 1) * 64) + (wo >> 1);
    const float* offp = t4 + (size_t)b * 1152 * 4096 + po;
    const float* xb = x + (size_t)b * 64 * HX * WX;
    float acc[32];
    #pragma unroll
    for (int i = 0; i < 32; ++i) acc[i] = 0.f;

    for (int c = 0; c < 64; ++c) {
        const float* xp = xb + (size_t)c * HX * WX;
        float v[9];
        #pragma unroll
        for (int kk = 0; kk < 9; ++kk) {
            float oy = offp[(size_t)((c * 9 + kk) * 2) * 4096];
            float ox = offp[(size_t)((c * 9 + kk) * 2 + 1) * 4096];
            float py = oy + (float)ho + (float)(kk / 3);
            float px = ox + (float)wo + (float)(kk % 3);
            float y0f = floorf(py), x0f = floorf(px);
            float fy = py - y0f, fx = px - x0f;
            int y0 = (int)y0f, x0 = (int)x0f;
            float s = 0.f;
            #pragma unroll
            for (int dy = 0; dy < 2; ++dy) {
                int yy = y0 + dy;
                float wy = dy ? fy : (1.f - fy);
                bool vy = (yy >= 0) && (yy < HX);
                int yc = min(max(yy, 0), HX - 1);
                #pragma unroll
                for (int dx = 0; dx < 2; ++dx) {
                    int xx = x0 + dx;
                    float wv = dx ? fx : (1.f - fx);
                    bool vx = (xx >= 0) && (xx < WX);
                    int xc = min(max(xx, 0), WX - 1);
                    float m = (vy && vx) ? 1.f : 0.f;
                    float val = xp[yc * WX + xc];
                    s += wy * wv * m * val;
                }
            }
            v[kk] = s;
        }
        // wdt layout: [c][o][9], contiguous 288 floats for this (c, half)
        const float* wp = wdt + ((size_t)c * 64 + half * 32) * 9;
        #pragma unroll
        for (int o = 0; o < 32; ++o) {
            float s2 = acc[o];
            #pragma unroll
            for (int k = 0; k < 9; ++k) s2 += wp[o * 9 + k] * v[k];
            acc[o] = s2;
        }
    }
    float* op = out + (((size_t)b * 64 + half * 32) * 128) * 128 + ho * 128 + wo;
    #pragma unroll
    for (int o = 0; o < 32; ++o) op[(size_t)o * 128 * 128] = acc[o];
}

extern "C" void kernel_launch(void* const* d_in, const int* in_sizes, int n_in,
                              void* d_out, int out_size, void* d_ws, size_t ws_size,
                              hipStream_t stream) {
    const float* x  = (const float*)d_in[0];
    const float* w0 = (const float*)d_in[1];
    const float* b0 = (const float*)d_in[2];
    const float* w1 = (const float*)d_in[3];
    const float* b1 = (const float*)d_in[4];
    const float* w2 = (const float*)d_in[5];
    const float* b2 = (const float*)d_in[6];
    const float* w3 = (const float*)d_in[7];
    const float* b3 = (const float*)d_in[8];
    const float* wd = (const float*)d_in[9];
    float* out = (float*)d_out;

    // ws layout (floats)
    float* ws = (float*)d_ws;
    float* p1  = ws;                         // 4*64*64*64   = 1,048,576
    float* t2  = p1 + 1048576;               // 4*32*64*64   =   524,288
    float* t3  = t2 + 524288;                // 4*32*64*64   =   524,288
    float* t4  = t3 + 524288;                // 4*1152*64*64 = 18,874,368
    float* wdt = t4 + 18874368;              // 64*64*9      =    36,864
    // total ~84 MB

    k_wdt<<<144, 256, 0, stream>>>(wd, wdt);
    k_conv0_pool<<<4096, 256, 0, stream>>>(x, w0, b0, p1);
    k_conv1x1_a<<<256, 256, 0, stream>>>(p1, w1, b1, t2);
    k_conv3x3_b<<<256, 256, 0, stream>>>(t2, w2, b2, t3);
    k_conv1x1_off<<<1152, 256, 0, stream>>>(t3, w3, b3, t4);
    k_deform<<<512, 256, 0, stream>>>(x, t4, wdt, out);
}

// Round 2
// 670.552 us; speedup vs baseline: 1.6558x; 1.6558x over previous
//
#include <hip/hip_runtime.h>
#include <hip/hip_bf16.h>

// Pipeline:
//  x (4,64,130,130) --conv3x3 valid + bias + maxpool2x2--> p1 (4,64,64,64)
//  p1 --1x1 conv (64->32)--> t2 (4,32,64,64)
//  t2 --3x3 conv pad=1 (32->32)--> t3 (4,32,64,64)
//  t3 --1x1 conv (32->1152)--> t4t (4, 4096 px, 1152 ch)  [PIXEL-MAJOR offset field]
//  deform_conv(x, upsample2x(offsets), wd) -> out (4,64,128,128)
//  (upsample fused into deform: read t4t at po=(ho>>1)*64+(wo>>1))

#define HX 130
#define WX 130

// ---------------- K0: transpose wd (o,c,9) -> (c,o,9)
__global__ __launch_bounds__(256) void k_wdt(const float* __restrict__ wd,
                                             float* __restrict__ wdt) {
    int idx = blockIdx.x * 256 + threadIdx.x;   // 64*64*9 = 36864
    if (idx >= 36864) return;
    int k = idx % 9;
    int rem = idx / 9;
    int c = rem & 63;
    int o = rem >> 6;
    wdt[(c * 64 + o) * 9 + k] = wd[idx];
}

// ---------------- K1: conv3x3 valid (64->64) + bias + maxpool 2x2 -> p1
// grid 512 = b(4) * cog(8) * tile(16); block 256 = 4 pooled rows x 64 cols
// Each block computes 8 output channels -> 8x input-slab reuse per LDS load.
__global__ __launch_bounds__(256) void k_conv0_pool(const float* __restrict__ x,
                                                    const float* __restrict__ w0,
                                                    const float* __restrict__ b0,
                                                    float* __restrict__ p1) {
    int blk = blockIdx.x;
    int tile = blk & 15;
    int cog = (blk >> 4) & 7;     // blockIdx-derived -> weight loads are scalar
    int b = blk >> 7;
    int tid = threadIdx.x;
    int pw = tid & 63;
    int phl = tid >> 6;           // 0..3
    int ph = tile * 4 + phl;
    __shared__ float slab[10 * WX];
    const float* xb = x + (size_t)(b * 64) * HX * WX;
    int row0 = tile * 8;
    float acc[8][4];
    #pragma unroll
    for (int i = 0; i < 8; ++i)
        #pragma unroll
        for (int j = 0; j < 4; ++j) acc[i][j] = 0.f;

    for (int ci = 0; ci < 64; ++ci) {
        __syncthreads();
        const float* xp = xb + (size_t)ci * HX * WX + row0 * WX;
        for (int i = tid; i < 10 * WX; i += 256) slab[i] = xp[i];
        __syncthreads();
        float v[4][4];
        #pragma unroll
        for (int r = 0; r < 4; ++r)
            #pragma unroll
            for (int cc = 0; cc < 4; ++cc)
                v[r][cc] = slab[(2 * phl + r) * WX + 2 * pw + cc];
        #pragma unroll
        for (int i = 0; i < 8; ++i) {
            const float* wp = w0 + (((cog * 8 + i) * 64) + ci) * 9;  // uniform
            float w[9];
            #pragma unroll
            for (int k = 0; k < 9; ++k) w[k] = wp[k];
            #pragma unroll
            for (int dr = 0; dr < 2; ++dr)
                #pragma unroll
                for (int dc = 0; dc < 2; ++dc) {
                    float s = acc[i][dr * 2 + dc];
                    #pragma unroll
                    for (int ky = 0; ky < 3; ++ky)
                        #pragma unroll
                        for (int kx = 0; kx < 3; ++kx)
                            s += w[ky * 3 + kx] * v[dr + ky][dc + kx];
                    acc[i][dr * 2 + dc] = s;
                }
        }
    }
    #pragma unroll
    for (int i = 0; i < 8; ++i) {
        float m = fmaxf(fmaxf(acc[i][0], acc[i][1]), fmaxf(acc[i][2], acc[i][3]))
                + b0[cog * 8 + i];
        p1[(((size_t)b * 64 + cog * 8 + i) * 64 + ph) * 64 + pw] = m;
    }
}

// ---------------- K2: 1x1 conv 64->32 on 64x64
// grid 256 = b(4)*cog(4)*pt(16)
__global__ __launch_bounds__(256) void k_conv1x1_a(const float* __restrict__ p1,
                                                   const float* __restrict__ w1,
                                                   const float* __restrict__ b1,
                                                   float* __restrict__ t2) {
    int blk = blockIdx.x;
    int pt = blk & 15;
    int cog = (blk >> 4) & 3;
    int b = blk >> 6;
    int p = pt * 256 + threadIdx.x;
    float acc[8];
    #pragma unroll
    for (int i = 0; i < 8; ++i) acc[i] = b1[cog * 8 + i];
    const float* ip = p1 + (size_t)b * 64 * 4096 + p;
    for (int ci = 0; ci < 64; ++ci) {
        float v = ip[(size_t)ci * 4096];
        #pragma unroll
        for (int i = 0; i < 8; ++i) acc[i] += w1[(cog * 8 + i) * 64 + ci] * v;
    }
    float* op = t2 + (size_t)b * 32 * 4096 + p;
    #pragma unroll
    for (int i = 0; i < 8; ++i) op[(size_t)(cog * 8 + i) * 4096] = acc[i];
}

// ---------------- K3: 3x3 conv pad=1, 32->32 on 64x64
// grid 256 = b(4)*cog(4)*pt(16)
__global__ __launch_bounds__(256) void k_conv3x3_b(const float* __restrict__ t2,
                                                   const float* __restrict__ w2,
                                                   const float* __restrict__ b2,
                                                   float* __restrict__ t3) {
    int blk = blockIdx.x;
    int pt = blk & 15;
    int cog = (blk >> 4) & 3;
    int b = blk >> 6;
    int p = pt * 256 + threadIdx.x;
    int hy = p >> 6, wx = p & 63;
    float acc[8];
    #pragma unroll
    for (int i = 0; i < 8; ++i) acc[i] = b2[cog * 8 + i];
    const float* ip = t2 + (size_t)b * 32 * 4096;
    for (int ci = 0; ci < 32; ++ci) {
        float v[9];
        #pragma unroll
        for (int ky = 0; ky < 3; ++ky) {
            int yy = hy + ky - 1;
            #pragma unroll
            for (int kx = 0; kx < 3; ++kx) {
                int xx = wx + kx - 1;
                bool ok = (yy >= 0 && yy < 64 && xx >= 0 && xx < 64);
                int yc = min(max(yy, 0), 63), xc = min(max(xx, 0), 63);
                float val = ip[(size_t)ci * 4096 + yc * 64 + xc];
                v[ky * 3 + kx] = ok ? val : 0.f;
            }
        }
        #pragma unroll
        for (int i = 0; i < 8; ++i) {
            const float* wp = w2 + (((cog * 8 + i) * 32) + ci) * 9;   // uniform
            float s = acc[i];
            #pragma unroll
            for (int k = 0; k < 9; ++k) s += wp[k] * v[k];
            acc[i] = s;
        }
    }
    float* op = t3 + (size_t)b * 32 * 4096 + p;
    #pragma unroll
    for (int i = 0; i < 8; ++i) op[(size_t)(cog * 8 + i) * 4096] = acc[i];
}

// ---------------- K4: 1x1 conv 32->1152, output PIXEL-MAJOR t4t[b][p][1152]
// grid 1152 = b(4)*chg(18)*pt(16); thread computes 64 consecutive channels of one pixel
__global__ __launch_bounds__(256) void k_conv1x1_off(const float* __restrict__ t3,
                                                     const float* __restrict__ w3,
                                                     const float* __restrict__ b3,
                                                     float* __restrict__ t4t) {
    int blk = blockIdx.x;
    int pt = blk & 15;
    int g2 = blk >> 4;            // 0..71
    int chg = g2 % 18;            // blockIdx-derived -> scalar weight loads
    int b = g2 / 18;
    int p = pt * 256 + threadIdx.x;
    float v[32];
    const float* ip = t3 + (size_t)b * 32 * 4096 + p;
    #pragma unroll
    for (int ci = 0; ci < 32; ++ci) v[ci] = ip[(size_t)ci * 4096];
    float* op = t4t + ((size_t)b * 4096 + p) * 1152;
    for (int j4 = 0; j4 < 16; ++j4) {
        float4 r;
        float* rp = &r.x;
        #pragma unroll
        for (int u = 0; u < 4; ++u) {
            int ch = chg * 64 + j4 * 4 + u;
            float acc = b3[ch];
            const float* wp = w3 + ch * 32;      // uniform
            #pragma unroll
            for (int ci = 0; ci < 32; ++ci) acc += wp[ci] * v[ci];
            rp[u] = acc;
        }
        *(float4*)(op + chg * 64 + j4 * 4) = r;  // 256B-aligned contiguous
    }
}

// ---------------- K5: deformable conv (fused 2x upsample of offsets)
// grid 1024 = b(4) * q(4) * tile(64); thread per output pixel, 16 couts (quarter)
__global__ __launch_bounds__(256) void k_deform(const float* __restrict__ x,
                                                const float* __restrict__ t4t,
                                                const float* __restrict__ wdt,
                                                float* __restrict__ out) {
    int blk = blockIdx.x;
    int t = blk & 63;
    int q = (blk >> 6) & 3;       // blockIdx-derived -> scalar weight loads
    int b = blk >> 8;
    int pix = t * 256 + threadIdx.x;    // 0..16383
    int wo = pix & 127;
    int ho = pix >> 7;
    int po = ((ho >> 1) * 64) + (wo >> 1);
    const float* offp = t4t + ((size_t)b * 4096 + po) * 1152;
    const float* xb = x + (size_t)b * 64 * HX * WX;
    float acc[16];
    #pragma unroll
    for (int i = 0; i < 16; ++i) acc[i] = 0.f;

    for (int c = 0; c < 64; ++c) {
        const float* xp = xb + (size_t)c * HX * WX;
        // 18 contiguous offsets for this (pixel, channel): 9 x float2 (8B aligned)
        const float2* o2 = (const float2*)(offp + c * 18);
        float2 od[9];
        #pragma unroll
        for (int kk = 0; kk < 9; ++kk) od[kk] = o2[kk];
        float v[9];
        #pragma unroll
        for (int kk = 0; kk < 9; ++kk) {
            float py = od[kk].x + (float)ho + (float)(kk / 3);
            float px = od[kk].y + (float)wo + (float)(kk % 3);
            float y0f = floorf(py), x0f = floorf(px);
            float fy = py - y0f, fx = px - x0f;
            int y0 = (int)y0f, x0 = (int)x0f;
            int y1 = y0 + 1, x1 = x0 + 1;
            bool vy0 = (y0 >= 0) & (y0 < HX);
            bool vy1 = (y1 >= 0) & (y1 < HX);
            bool vx0 = (x0 >= 0) & (x0 < WX);
            bool vx1 = (x1 >= 0) & (x1 < WX);
            int y0c = min(max(y0, 0), HX - 1), y1c = min(max(y1, 0), HX - 1);
            int x0c = min(max(x0, 0), WX - 1), x1c = min(max(x1, 0), WX - 1);
            float t00 = xp[y0c * WX + x0c];
            float t01 = xp[y0c * WX + x1c];
            float t10 = xp[y1c * WX + x0c];
            float t11 = xp[y1c * WX + x1c];
            float v00 = (vy0 & vx0) ? t00 : 0.f;
            float v01 = (vy0 & vx1) ? t01 : 0.f;
            float v10 = (vy1 & vx0) ? t10 : 0.f;
            float v11 = (vy1 & vx1) ? t11 : 0.f;
            float top = v00 + fx * (v01 - v00);
            float bot = v10 + fx * (v11 - v10);
            v[kk] = top + fy * (bot - top);
        }
        const float* wp = wdt + ((size_t)c * 64 + q * 16) * 9;  // uniform -> s_load
        #pragma unroll
        for (int o = 0; o < 16; ++o) {
            float s2 = acc[o];
            #pragma unroll
            for (int k = 0; k < 9; ++k) s2 += wp[o * 9 + k] * v[k];
            acc[o] = s2;
        }
    }
    float* op = out + (((size_t)b * 64 + q * 16) * 128 + ho) * 128 + wo;
    #pragma unroll
    for (int o = 0; o < 16; ++o) op[(size_t)o * 128 * 128] = acc[o];
}

extern "C" void kernel_launch(void* const* d_in, const int* in_sizes, int n_in,
                              void* d_out, int out_size, void* d_ws, size_t ws_size,
                              hipStream_t stream) {
    const float* x  = (const float*)d_in[0];
    const float* w0 = (const float*)d_in[1];
    const float* b0 = (const float*)d_in[2];
    const float* w1 = (const float*)d_in[3];
    const float* b1 = (const float*)d_in[4];
    const float* w2 = (const float*)d_in[5];
    const float* b2 = (const float*)d_in[6];
    const float* w3 = (const float*)d_in[7];
    const float* b3 = (const float*)d_in[8];
    const float* wd = (const float*)d_in[9];
    float* out = (float*)d_out;

    // ws layout (floats) — identical total to round 1 (84.03 MB)
    float* ws = (float*)d_ws;
    float* p1  = ws;                         // 1,048,576
    float* t2  = p1 + 1048576;               //   524,288
    float* t3  = t2 + 524288;                //   524,288
    float* t4t = t3 + 524288;                // 18,874,368 (pixel-major)
    float* wdt = t4t + 18874368;             //    36,864

    k_wdt<<<144, 256, 0, stream>>>(wd, wdt);
    k_conv0_pool<<<512, 256, 0, stream>>>(x, w0, b0, p1);
    k_conv1x1_a<<<256, 256, 0, stream>>>(p1, w1, b1, t2);
    k_conv3x3_b<<<256, 256, 0, stream>>>(t2, w2, b2, t3);
    k_conv1x1_off<<<1152, 256, 0, stream>>>(t3, w3, b3, t4t);
    k_deform<<<1024, 256, 0, stream>>>(x, t4t, wdt, out);
}

// Round 3
// 539.625 us; speedup vs baseline: 2.0576x; 1.2426x over previous
//
#include <hip/hip_runtime.h>
#include <hip/hip_bf16.h>

// Pipeline:
//  x (4,64,130,130) --conv3x3 valid + bias + maxpool2x2--> p1 (4,64,64,64)
//  p1 --1x1 conv (64->32)--> t2 (4,32,64,64)
//  t2 --3x3 conv pad=1 (32->32)--> t3 (4,32,64,64)
//  t3 --1x1 conv (32->1152)--> t4t (4, 4096 px, 1152 ch)  [PIXEL-MAJOR offset field]
//  deform_conv(x, upsample2x(offsets), wd) -> out (4,64,128,128)
//  Deform: offsets at half res => each 2x2 output quad shares (fy,fx); its 16
//  bilinear taps collapse to a 3x3 grid. Phase1 computes v once per
//  (quad,ch,kk) into LDS; phase2 is a small GEMM from LDS.

#define HX 130
#define WX 130

// ---------------- K0: wd (o,c,3,3) -> wdt2[(c*9+k)*64 + o]  (k-major for deform phase 2)
__global__ __launch_bounds__(256) void k_wdt(const float* __restrict__ wd,
                                             float* __restrict__ wdt2) {
    int idx = blockIdx.x * 256 + threadIdx.x;   // 64*64*9 = 36864
    if (idx >= 36864) return;
    int k = idx % 9;
    int rem = idx / 9;        // o*64 + c
    int c = rem & 63;
    int o = rem >> 6;
    wdt2[(c * 9 + k) * 64 + o] = wd[idx];
}

// ---------------- K1: conv3x3 valid (64->64) + bias + maxpool 2x2 -> p1
// grid 512 = b(4) * cog(8) * tile(16); block 256 = 4 pooled rows x 64 cols
// Register-prefetch pipeline: load slab for ci+1 while computing ci.
__global__ __launch_bounds__(256) void k_conv0_pool(const float* __restrict__ x,
                                                    const float* __restrict__ w0,
                                                    const float* __restrict__ b0,
                                                    float* __restrict__ p1) {
    int blk = blockIdx.x;
    int tile = blk & 15;
    int cog = (blk >> 4) & 7;     // blockIdx-derived -> weight loads are scalar
    int b = blk >> 7;
    int tid = threadIdx.x;
    int pw = tid & 63;
    int phl = tid >> 6;           // 0..3
    int ph = tile * 4 + phl;
    __shared__ float slab[10 * WX];
    const float* xb = x + (size_t)(b * 64) * HX * WX;
    int row0 = tile * 8;
    const float* xbase = xb + row0 * WX;
    float acc[8][4];
    #pragma unroll
    for (int i = 0; i < 8; ++i)
        #pragma unroll
        for (int j = 0; j < 4; ++j) acc[i][j] = 0.f;

    float pre[6];
    #pragma unroll
    for (int j = 0; j < 6; ++j) {
        int i = tid + j * 256;
        pre[j] = (i < 10 * WX) ? xbase[i] : 0.f;
    }

    for (int ci = 0; ci < 64; ++ci) {
        __syncthreads();
        #pragma unroll
        for (int j = 0; j < 6; ++j) {
            int i = tid + j * 256;
            if (i < 10 * WX) slab[i] = pre[j];
        }
        __syncthreads();
        if (ci < 63) {
            const float* xp = xbase + (size_t)(ci + 1) * (HX * WX);
            #pragma unroll
            for (int j = 0; j < 6; ++j) {
                int i = tid + j * 256;
                pre[j] = (i < 10 * WX) ? xp[i] : 0.f;
            }
        }
        float v[4][4];
        #pragma unroll
        for (int r = 0; r < 4; ++r)
            #pragma unroll
            for (int cc = 0; cc < 4; ++cc)
                v[r][cc] = slab[(2 * phl + r) * WX + 2 * pw + cc];
        #pragma unroll
        for (int i = 0; i < 8; ++i) {
            const float* wp = w0 + (((cog * 8 + i) * 64) + ci) * 9;  // uniform
            float w[9];
            #pragma unroll
            for (int k = 0; k < 9; ++k) w[k] = wp[k];
            #pragma unroll
            for (int dr = 0; dr < 2; ++dr)
                #pragma unroll
                for (int dc = 0; dc < 2; ++dc) {
                    float s = acc[i][dr * 2 + dc];
                    #pragma unroll
                    for (int ky = 0; ky < 3; ++ky)
                        #pragma unroll
                        for (int kx = 0; kx < 3; ++kx)
                            s += w[ky * 3 + kx] * v[dr + ky][dc + kx];
                    acc[i][dr * 2 + dc] = s;
                }
        }
    }
    #pragma unroll
    for (int i = 0; i < 8; ++i) {
        float m = fmaxf(fmaxf(acc[i][0], acc[i][1]), fmaxf(acc[i][2], acc[i][3]))
                + b0[cog * 8 + i];
        p1[(((size_t)b * 64 + cog * 8 + i) * 64 + ph) * 64 + pw] = m;
    }
}

// ---------------- K2: 1x1 conv 64->32 on 64x64
// grid 512 = b(4)*cog(8)*pt(16); 4 outs per thread
__global__ __launch_bounds__(256) void k_conv1x1_a(const float* __restrict__ p1,
                                                   const float* __restrict__ w1,
                                                   const float* __restrict__ b1,
                                                   float* __restrict__ t2) {
    int blk = blockIdx.x;
    int pt = blk & 15;
    int cog = (blk >> 4) & 7;
    int b = blk >> 7;
    int p = pt * 256 + threadIdx.x;
    float acc[4];
    #pragma unroll
    for (int i = 0; i < 4; ++i) acc[i] = b1[cog * 4 + i];
    const float* ip = p1 + (size_t)b * 64 * 4096 + p;
    for (int ci = 0; ci < 64; ++ci) {
        float v = ip[(size_t)ci * 4096];
        #pragma unroll
        for (int i = 0; i < 4; ++i) acc[i] += w1[(cog * 4 + i) * 64 + ci] * v;
    }
    float* op = t2 + (size_t)b * 32 * 4096 + p;
    #pragma unroll
    for (int i = 0; i < 4; ++i) op[(size_t)(cog * 4 + i) * 4096] = acc[i];
}

// ---------------- K3: 3x3 conv pad=1, 32->32 on 64x64
// grid 512 = b(4)*cog(8)*pt(16); 4 outs per thread
__global__ __launch_bounds__(256) void k_conv3x3_b(const float* __restrict__ t2,
                                                   const float* __restrict__ w2,
                                                   const float* __restrict__ b2,
                                                   float* __restrict__ t3) {
    int blk = blockIdx.x;
    int pt = blk & 15;
    int cog = (blk >> 4) & 7;
    int b = blk >> 7;
    int p = pt * 256 + threadIdx.x;
    int hy = p >> 6, wx = p & 63;
    float acc[4];
    #pragma unroll
    for (int i = 0; i < 4; ++i) acc[i] = b2[cog * 4 + i];
    const float* ip = t2 + (size_t)b * 32 * 4096;
    for (int ci = 0; ci < 32; ++ci) {
        float v[9];
        #pragma unroll
        for (int ky = 0; ky < 3; ++ky) {
            int yy = hy + ky - 1;
            #pragma unroll
            for (int kx = 0; kx < 3; ++kx) {
                int xx = wx + kx - 1;
                bool ok = (yy >= 0 && yy < 64 && xx >= 0 && xx < 64);
                int yc = min(max(yy, 0), 63), xc = min(max(xx, 0), 63);
                float val = ip[(size_t)ci * 4096 + yc * 64 + xc];
                v[ky * 3 + kx] = ok ? val : 0.f;
            }
        }
        #pragma unroll
        for (int i = 0; i < 4; ++i) {
            const float* wp = w2 + (((cog * 4 + i) * 32) + ci) * 9;   // uniform
            float s = acc[i];
            #pragma unroll
            for (int k = 0; k < 9; ++k) s += wp[k] * v[k];
            acc[i] = s;
        }
    }
    float* op = t3 + (size_t)b * 32 * 4096 + p;
    #pragma unroll
    for (int i = 0; i < 4; ++i) op[(size_t)(cog * 4 + i) * 4096] = acc[i];
}

// ---------------- K4: 1x1 conv 32->1152, output PIXEL-MAJOR t4t[b][p][1152]
// grid 1152 = b(4)*chg(18)*pt(16)
__global__ __launch_bounds__(256) void k_conv1x1_off(const float* __restrict__ t3,
                                                     const float* __restrict__ w3,
                                                     const float* __restrict__ b3,
                                                     float* __restrict__ t4t) {
    int blk = blockIdx.x;
    int pt = blk & 15;
    int g2 = blk >> 4;            // 0..71
    int chg = g2 % 18;            // blockIdx-derived -> scalar weight loads
    int b = g2 / 18;
    int p = pt * 256 + threadIdx.x;
    float v[32];
    const float* ip = t3 + (size_t)b * 32 * 4096 + p;
    #pragma unroll
    for (int ci = 0; ci < 32; ++ci) v[ci] = ip[(size_t)ci * 4096];
    float* op = t4t + ((size_t)b * 4096 + p) * 1152;
    for (int j4 = 0; j4 < 16; ++j4) {
        float4 r;
        float* rp = &r.x;
        #pragma unroll
        for (int u = 0; u < 4; ++u) {
            int ch = chg * 64 + j4 * 4 + u;
            float acc = b3[ch];
            const float* wp = w3 + ch * 32;      // uniform
            #pragma unroll
            for (int ci = 0; ci < 32; ++ci) acc += wp[ci] * v[ci];
            rp[u] = acc;
        }
        *(float4*)(op + chg * 64 + j4 * 4) = r;
    }
}

// ---------------- K5: deformable conv, two-phase LDS structure
// grid 512 = b(4) * ty(16) * tx(8); block 256; tile = 16x8 output px = 32 quads
// thread: og = tid>>5 (8 out-channel groups of 8), qd = tid&31 (quad)
__global__ __launch_bounds__(256, 4) void k_deform(const float* __restrict__ x,
                                                   const float* __restrict__ t4t,
                                                   const float* __restrict__ wdt2,
                                                   float* __restrict__ out) {
    int blk = blockIdx.x;
    int tx = blk & 7;
    int ty = (blk >> 3) & 15;
    int b = blk >> 7;
    int tid = threadIdx.x;
    int og = tid >> 5;            // 0..7
    int qd = tid & 31;            // 0..31
    int qx = tx * 8 + (qd & 7);   // global quad col 0..63
    int qy = ty * 4 + (qd >> 3);  // global quad row 0..63

    __shared__ __align__(16) float vlds[72 * 32 * 4];   // [ckk][quad][sub] 36864 B

    float acc[8][4];
    #pragma unroll
    for (int o = 0; o < 8; ++o)
        #pragma unroll
        for (int s = 0; s < 4; ++s) acc[o][s] = 0.f;

    const float* xb = x + (size_t)b * 64 * HX * WX;
    int po = qy * 64 + qx;
    const float* offp = t4t + ((size_t)b * 4096 + po) * 1152;

    for (int chunk = 0; chunk < 8; ++chunk) {
        __syncthreads();          // protect vlds from previous chunk's readers
        // ---- phase 1: bilinear samples, one task per (quad, ch, kk)
        // 2304 tasks = 9 iters * 256 threads; q==qd, ckk = it*8+og
        #pragma unroll
        for (int it = 0; it < 9; ++it) {
            int ckk = it * 8 + og;       // 0..71
            int ch = ckk / 9;
            int kk = ckk - ch * 9;
            int c = chunk * 8 + ch;
            float2 off = *(const float2*)(offp + c * 18 + kk * 2);
            float py = off.x + (float)(2 * qy + kk / 3);
            float px = off.y + (float)(2 * qx + kk % 3);
            float y0f = floorf(py), x0f = floorf(px);
            float fy = py - y0f, fx = px - x0f;
            int y0 = (int)y0f, x0 = (int)x0f;
            const float* xp = xb + (size_t)c * (HX * WX);
            float t[3][3];
            #pragma unroll
            for (int r = 0; r < 3; ++r) {
                int yy = y0 + r;
                bool vy = (yy >= 0) & (yy < HX);
                int yc = min(max(yy, 0), HX - 1);
                #pragma unroll
                for (int s = 0; s < 3; ++s) {
                    int xx = x0 + s;
                    bool vx = (xx >= 0) & (xx < WX);
                    int xc = min(max(xx, 0), WX - 1);
                    float val = xp[yc * WX + xc];
                    t[r][s] = (vy & vx) ? val : 0.f;
                }
            }
            float h0[3], h1[3];
            #pragma unroll
            for (int r = 0; r < 3; ++r) {
                h0[r] = t[r][0] + fx * (t[r][1] - t[r][0]);
                h1[r] = t[r][1] + fx * (t[r][2] - t[r][1]);
            }
            float4 vv;
            vv.x = h0[0] + fy * (h0[1] - h0[0]);   // sub (0,0)
            vv.y = h1[0] + fy * (h1[1] - h1[0]);   // sub (0,1)
            vv.z = h0[1] + fy * (h0[2] - h0[1]);   // sub (1,0)
            vv.w = h1[1] + fy * (h1[2] - h1[1]);   // sub (1,1)
            *(float4*)&vlds[(ckk * 32 + qd) * 4] = vv;
        }
        __syncthreads();
        // ---- phase 2: acc[8 outs][4 sub] += w * v from LDS
        #pragma unroll 1
        for (int ch = 0; ch < 8; ++ch) {
            const float* wp = wdt2 + (size_t)((chunk * 8 + ch) * 9) * 64 + og * 8;
            const float* vp = &vlds[(ch * 9) * 128 + qd * 4];
            #pragma unroll
            for (int k = 0; k < 9; ++k) {
                float4 vv = *(const float4*)(vp + k * 128);
                float4 wa = *(const float4*)(wp + k * 64);
                float4 wb = *(const float4*)(wp + k * 64 + 4);
                float wv[8] = {wa.x, wa.y, wa.z, wa.w, wb.x, wb.y, wb.z, wb.w};
                #pragma unroll
                for (int o = 0; o < 8; ++o) {
                    acc[o][0] += wv[o] * vv.x;
                    acc[o][1] += wv[o] * vv.y;
                    acc[o][2] += wv[o] * vv.z;
                    acc[o][3] += wv[o] * vv.w;
                }
            }
        }
    }
    // ---- epilogue: quad (2x2) stores as float2 pairs
    int ho = 2 * qy, wo = 2 * qx;
    #pragma unroll
    for (int o = 0; o < 8; ++o) {
        int oc = og * 8 + o;
        float* op = out + (((size_t)b * 64 + oc) * 128 + ho) * 128 + wo;
        *(float2*)op = make_float2(acc[o][0], acc[o][1]);
        *(float2*)(op + 128) = make_float2(acc[o][2], acc[o][3]);
    }
}

extern "C" void kernel_launch(void* const* d_in, const int* in_sizes, int n_in,
                              void* d_out, int out_size, void* d_ws, size_t ws_size,
                              hipStream_t stream) {
    const float* x  = (const float*)d_in[0];
    const float* w0 = (const float*)d_in[1];
    const float* b0 = (const float*)d_in[2];
    const float* w1 = (const float*)d_in[3];
    const float* b1 = (const float*)d_in[4];
    const float* w2 = (const float*)d_in[5];
    const float* b2 = (const float*)d_in[6];
    const float* w3 = (const float*)d_in[7];
    const float* b3 = (const float*)d_in[8];
    const float* wd = (const float*)d_in[9];
    float* out = (float*)d_out;

    float* ws = (float*)d_ws;
    float* p1   = ws;                        // 1,048,576
    float* t2   = p1 + 1048576;              //   524,288
    float* t3   = t2 + 524288;               //   524,288
    float* t4t  = t3 + 524288;               // 18,874,368 (pixel-major)
    float* wdt2 = t4t + 18874368;            //    36,864 (k-major)

    k_wdt<<<144, 256, 0, stream>>>(wd, wdt2);
    k_conv0_pool<<<512, 256, 0, stream>>>(x, w0, b0, p1);
    k_conv1x1_a<<<512, 256, 0, stream>>>(p1, w1, b1, t2);
    k_conv3x3_b<<<512, 256, 0, stream>>>(t2, w2, b2, t3);
    k_conv1x1_off<<<1152, 256, 0, stream>>>(t3, w3, b3, t4t);
    k_deform<<<512, 256, 0, stream>>>(x, t4t, wdt2, out);
}

// Round 4
// 338.465 us; speedup vs baseline: 3.2805x; 1.5943x over previous
//
#include <hip/hip_runtime.h>
#include <hip/hip_bf16.h>

// Pipeline:
//  x (4,64,130,130) --conv3x3 valid + bias + maxpool2x2--> p1 (4,64,64,64)
//  p1 --1x1 conv (64->32)--> t2 (4,32,64,64)
//  t2 --3x3 conv pad=1 (32->32)--> t3 (4,32,64,64)
//  t3 --1x1 conv (32->1152)--> t4 (4,1152,4096)  [CHANNEL-major offset field]
//  deform_conv(x, upsample2x(offsets), wd) -> out (4,64,128,128)
//  Deform: offsets at half res => 2x2 output quad shares (fy,fx); 16 bilinear
//  taps collapse to a 3x3 grid. Block = strip of 16 consecutive po (one quad
//  row segment). Offsets staged to LDS coalesced (reg-prefetched); phase1
//  computes v once per (quad,ch,kk) into LDS; phase2 = small GEMM from LDS.

#define HX 130
#define WX 130

// ---------------- K0: wd (o,c,3,3) -> wdt2[(c*9+k)*64 + o]  (k-major)
__global__ __launch_bounds__(256) void k_wdt(const float* __restrict__ wd,
                                             float* __restrict__ wdt2) {
    int idx = blockIdx.x * 256 + threadIdx.x;   // 64*64*9 = 36864
    if (idx >= 36864) return;
    int k = idx % 9;
    int rem = idx / 9;        // o*64 + c
    int c = rem & 63;
    int o = rem >> 6;
    wdt2[(c * 9 + k) * 64 + o] = wd[idx];
}

// ---------------- K1: conv3x3 valid (64->64) + bias + maxpool 2x2 -> p1
// grid 1024; swizzled so the 16 cog-blocks sharing a slab land on one XCD.
// block 256 = 4 pooled rows x 64 cols; 4 out-channels per block.
__global__ __launch_bounds__(256) void k_conv0_pool(const float* __restrict__ x,
                                                    const float* __restrict__ w0,
                                                    const float* __restrict__ b0,
                                                    float* __restrict__ p1) {
    int idx = blockIdx.x;
    int xcd = idx & 7;
    int r = idx >> 3;
    int cog = r & 15;             // blockIdx-derived -> weight loads scalar
    int phi = r >> 4;             // 0..7
    int p = phi * 8 + xcd;        // 0..63 (b,tile)
    int b = p >> 4;
    int tile = p & 15;
    int tid = threadIdx.x;
    int pw = tid & 63;
    int phl = tid >> 6;           // 0..3
    int ph = tile * 4 + phl;
    __shared__ float slab[10 * WX];
    const float* xb = x + (size_t)(b * 64) * HX * WX;
    int row0 = tile * 8;
    const float* xbase = xb + row0 * WX;
    float acc[4][4];
    #pragma unroll
    for (int i = 0; i < 4; ++i)
        #pragma unroll
        for (int j = 0; j < 4; ++j) acc[i][j] = 0.f;

    float pre[6];
    #pragma unroll
    for (int j = 0; j < 6; ++j) {
        int i = tid + j * 256;
        pre[j] = (i < 10 * WX) ? xbase[i] : 0.f;
    }

    for (int ci = 0; ci < 64; ++ci) {
        __syncthreads();
        #pragma unroll
        for (int j = 0; j < 6; ++j) {
            int i = tid + j * 256;
            if (i < 10 * WX) slab[i] = pre[j];
        }
        __syncthreads();
        if (ci < 63) {
            const float* xp = xbase + (size_t)(ci + 1) * (HX * WX);
            #pragma unroll
            for (int j = 0; j < 6; ++j) {
                int i = tid + j * 256;
                pre[j] = (i < 10 * WX) ? xp[i] : 0.f;
            }
        }
        float v[4][4];
        #pragma unroll
        for (int r2 = 0; r2 < 4; ++r2)
            #pragma unroll
            for (int cc = 0; cc < 4; ++cc)
                v[r2][cc] = slab[(2 * phl + r2) * WX + 2 * pw + cc];
        #pragma unroll
        for (int i = 0; i < 4; ++i) {
            const float* wp = w0 + (((cog * 4 + i) * 64) + ci) * 9;  // uniform
            float w[9];
            #pragma unroll
            for (int k = 0; k < 9; ++k) w[k] = wp[k];
            #pragma unroll
            for (int dr = 0; dr < 2; ++dr)
                #pragma unroll
                for (int dc = 0; dc < 2; ++dc) {
                    float s = acc[i][dr * 2 + dc];
                    #pragma unroll
                    for (int ky = 0; ky < 3; ++ky)
                        #pragma unroll
                        for (int kx = 0; kx < 3; ++kx)
                            s += w[ky * 3 + kx] * v[dr + ky][dc + kx];
                    acc[i][dr * 2 + dc] = s;
                }
        }
    }
    #pragma unroll
    for (int i = 0; i < 4; ++i) {
        float m = fmaxf(fmaxf(acc[i][0], acc[i][1]), fmaxf(acc[i][2], acc[i][3]))
                + b0[cog * 4 + i];
        p1[(((size_t)b * 64 + cog * 4 + i) * 64 + ph) * 64 + pw] = m;
    }
}

// ---------------- K2: 1x1 conv 64->32 on 64x64; grid 512
__global__ __launch_bounds__(256) void k_conv1x1_a(const float* __restrict__ p1,
                                                   const float* __restrict__ w1,
                                                   const float* __restrict__ b1,
                                                   float* __restrict__ t2) {
    int blk = blockIdx.x;
    int pt = blk & 15;
    int cog = (blk >> 4) & 7;
    int b = blk >> 7;
    int p = pt * 256 + threadIdx.x;
    float acc[4];
    #pragma unroll
    for (int i = 0; i < 4; ++i) acc[i] = b1[cog * 4 + i];
    const float* ip = p1 + (size_t)b * 64 * 4096 + p;
    for (int ci = 0; ci < 64; ++ci) {
        float v = ip[(size_t)ci * 4096];
        #pragma unroll
        for (int i = 0; i < 4; ++i) acc[i] += w1[(cog * 4 + i) * 64 + ci] * v;
    }
    float* op = t2 + (size_t)b * 32 * 4096 + p;
    #pragma unroll
    for (int i = 0; i < 4; ++i) op[(size_t)(cog * 4 + i) * 4096] = acc[i];
}

// ---------------- K3: 3x3 conv pad=1, 32->32 on 64x64; grid 512
__global__ __launch_bounds__(256) void k_conv3x3_b(const float* __restrict__ t2,
                                                   const float* __restrict__ w2,
                                                   const float* __restrict__ b2,
                                                   float* __restrict__ t3) {
    int blk = blockIdx.x;
    int pt = blk & 15;
    int cog = (blk >> 4) & 7;
    int b = blk >> 7;
    int p = pt * 256 + threadIdx.x;
    int hy = p >> 6, wx = p & 63;
    float acc[4];
    #pragma unroll
    for (int i = 0; i < 4; ++i) acc[i] = b2[cog * 4 + i];
    const float* ip = t2 + (size_t)b * 32 * 4096;
    for (int ci = 0; ci < 32; ++ci) {
        float v[9];
        #pragma unroll
        for (int ky = 0; ky < 3; ++ky) {
            int yy = hy + ky - 1;
            #pragma unroll
            for (int kx = 0; kx < 3; ++kx) {
                int xx = wx + kx - 1;
                bool ok = (yy >= 0 && yy < 64 && xx >= 0 && xx < 64);
                int yc = min(max(yy, 0), 63), xc = min(max(xx, 0), 63);
                float val = ip[(size_t)ci * 4096 + yc * 64 + xc];
                v[ky * 3 + kx] = ok ? val : 0.f;
            }
        }
        #pragma unroll
        for (int i = 0; i < 4; ++i) {
            const float* wp = w2 + (((cog * 4 + i) * 32) + ci) * 9;   // uniform
            float s = acc[i];
            #pragma unroll
            for (int k = 0; k < 9; ++k) s += wp[k] * v[k];
            acc[i] = s;
        }
    }
    float* op = t3 + (size_t)b * 32 * 4096 + p;
    #pragma unroll
    for (int i = 0; i < 4; ++i) op[(size_t)(cog * 4 + i) * 4096] = acc[i];
}

// ---------------- K4: 1x1 conv 32->1152, CHANNEL-major t4[b][1152][4096]
// grid 4608 = b(4)*chg(72 groups of 16 ch)*pt(16); all loads/stores coalesced,
// weight reads wave-uniform (s_load).
__global__ __launch_bounds__(256) void k_conv1x1_off(const float* __restrict__ t3,
                                                     const float* __restrict__ w3,
                                                     const float* __restrict__ b3,
                                                     float* __restrict__ t4) {
    int blk = blockIdx.x;
    int pt = blk & 15;
    int rem = blk >> 4;           // 0..287
    int chg = rem % 72;           // blockIdx-derived -> scalar weight loads
    int b = rem / 72;
    int p = pt * 256 + threadIdx.x;
    float v[32];
    const float* ip = t3 + (size_t)b * 32 * 4096 + p;
    #pragma unroll
    for (int ci = 0; ci < 32; ++ci) v[ci] = ip[(size_t)ci * 4096];
    float* op = t4 + ((size_t)b * 1152) * 4096 + p;
    #pragma unroll
    for (int j = 0; j < 16; ++j) {
        int ch = chg * 16 + j;
        float acc = b3[ch];
        const float* wp = w3 + ch * 32;      // uniform
        #pragma unroll
        for (int ci = 0; ci < 32; ++ci) acc += wp[ci] * v[ci];
        op[(size_t)ch * 4096] = acc;         // coalesced
    }
}

// ---------------- K5: deformable conv, strip-tiled two-phase LDS structure
// grid 1024 = b(4) * strip(256); strip = 16 consecutive po (quads of one row).
// tid: og = tid>>4 (16 groups of 4 out-ch), q = tid&15 (quad in strip).
#define VP 292   // vlds quad pitch (72*4 + 4 pad): conflict-free b128 both phases
__global__ __launch_bounds__(256, 4) void k_deform(const float* __restrict__ x,
                                                   const float* __restrict__ t4,
                                                   const float* __restrict__ wdt2,
                                                   float* __restrict__ out) {
    int blk = blockIdx.x;
    int strip = blk & 255;
    int b = blk >> 8;
    int tid = threadIdx.x;
    int og = tid >> 4;            // 0..15
    int q = tid & 15;             // 0..15
    int po0 = strip * 16;
    int qy = po0 >> 6;            // whole strip is one quad-row
    int qx0 = po0 & 63;

    __shared__ float ofs[144 * 16];            // [s][po_l]  9216 B
    __shared__ __align__(16) float vlds[16 * VP];  // [q][ckk*4(+pad)] 18688 B

    float acc[4][4];
    #pragma unroll
    for (int o = 0; o < 4; ++o)
        #pragma unroll
        for (int s = 0; s < 4; ++s) acc[o][s] = 0.f;

    const float* xb = x + (size_t)b * 64 * HX * WX;
    const float* t4b = t4 + (size_t)b * 1152 * 4096 + po0;

    // prefetch chunk 0 offsets: 2304 floats = 9 per thread, coalesced lines
    float pre[9];
    #pragma unroll
    for (int j = 0; j < 9; ++j) {
        int i2 = j * 256 + tid;                   // s = i2>>4, pl = i2&15
        pre[j] = t4b[(size_t)(i2 >> 4) * 4096 + (i2 & 15)];
    }

    for (int chunk = 0; chunk < 8; ++chunk) {
        __syncthreads();          // prev phase1 done with ofs, prev phase2 done with vlds
        #pragma unroll
        for (int j = 0; j < 9; ++j) ofs[j * 256 + tid] = pre[j];
        if (chunk < 7) {
            const float* src = t4b + (size_t)(chunk + 1) * 144 * 4096;
            #pragma unroll
            for (int j = 0; j < 9; ++j) {
                int i2 = j * 256 + tid;
                pre[j] = src[(size_t)(i2 >> 4) * 4096 + (i2 & 15)];
            }
        }
        __syncthreads();          // ofs visible

        // ---- phase 1: 1152 tasks (16 q x 72 ckk), q-fast lanes
        #pragma unroll
        for (int it = 0; it < 5; ++it) {
            int idx = it * 256 + tid;
            if (idx < 1152) {
                int tq = idx & 15;
                int ckk = idx >> 4;               // 0..71 = ch*9+kk
                int ch = (ckk * 57) >> 9;         // /9
                int kk = ckk - ch * 9;
                int c = chunk * 8 + ch;
                float oy = ofs[(2 * ckk) * 16 + tq];      // conflict-free (q-fast)
                float ox = ofs[(2 * ckk + 1) * 16 + tq];
                float py = oy + (float)(2 * qy + kk / 3);
                float px = ox + (float)(2 * (qx0 + tq) + kk % 3);
                float y0f = floorf(py), x0f = floorf(px);
                float fy = py - y0f, fx = px - x0f;
                int y0 = (int)y0f, x0 = (int)x0f;
                const float* xp = xb + (size_t)c * (HX * WX);
                float t[3][3];
                #pragma unroll
                for (int r = 0; r < 3; ++r) {
                    int yy = y0 + r;
                    bool vy = (yy >= 0) & (yy < HX);
                    int yc = min(max(yy, 0), HX - 1);
                    #pragma unroll
                    for (int s = 0; s < 3; ++s) {
                        int xx = x0 + s;
                        bool vx = (xx >= 0) & (xx < WX);
                        int xc = min(max(xx, 0), WX - 1);
                        float val = xp[yc * WX + xc];
                        t[r][s] = (vy & vx) ? val : 0.f;
                    }
                }
                float h0[3], h1[3];
                #pragma unroll
                for (int r = 0; r < 3; ++r) {
                    h0[r] = t[r][0] + fx * (t[r][1] - t[r][0]);
                    h1[r] = t[r][1] + fx * (t[r][2] - t[r][1]);
                }
                float4 vv;
                vv.x = h0[0] + fy * (h0[1] - h0[0]);   // sub (0,0)
                vv.y = h1[0] + fy * (h1[1] - h1[0]);   // sub (0,1)
                vv.z = h0[1] + fy * (h0[2] - h0[1]);   // sub (1,0)
                vv.w = h1[1] + fy * (h1[2] - h1[1]);   // sub (1,1)
                *(float4*)&vlds[tq * VP + ckk * 4] = vv;
            }
        }
        __syncthreads();          // vlds visible

        // ---- phase 2: acc[4 outs][4 sub] += w * v
        for (int ch = 0; ch < 8; ++ch) {
            int c = chunk * 8 + ch;
            const float* wp = wdt2 + (size_t)(c * 9) * 64 + og * 4;
            const float* vp = &vlds[q * VP + (ch * 9) * 4];
            #pragma unroll
            for (int k = 0; k < 9; ++k) {
                float4 vv = *(const float4*)(vp + k * 4);
                float4 w4 = *(const float4*)(wp + k * 64);
                float wv[4] = {w4.x, w4.y, w4.z, w4.w};
                #pragma unroll
                for (int o = 0; o < 4; ++o) {
                    acc[o][0] += wv[o] * vv.x;
                    acc[o][1] += wv[o] * vv.y;
                    acc[o][2] += wv[o] * vv.z;
                    acc[o][3] += wv[o] * vv.w;
                }
            }
        }
    }
    // ---- epilogue
    int ho = 2 * qy, wo = 2 * (qx0 + q);
    #pragma unroll
    for (int o = 0; o < 4; ++o) {
        int oc = og * 4 + o;
        float* op = out + (((size_t)b * 64 + oc) * 128 + ho) * 128 + wo;
        *(float2*)op = make_float2(acc[o][0], acc[o][1]);
        *(float2*)(op + 128) = make_float2(acc[o][2], acc[o][3]);
    }
}

extern "C" void kernel_launch(void* const* d_in, const int* in_sizes, int n_in,
                              void* d_out, int out_size, void* d_ws, size_t ws_size,
                              hipStream_t stream) {
    const float* x  = (const float*)d_in[0];
    const float* w0 = (const float*)d_in[1];
    const float* b0 = (const float*)d_in[2];
    const float* w1 = (const float*)d_in[3];
    const float* b1 = (const float*)d_in[4];
    const float* w2 = (const float*)d_in[5];
    const float* b2 = (const float*)d_in[6];
    const float* w3 = (const float*)d_in[7];
    const float* b3 = (const float*)d_in[8];
    const float* wd = (const float*)d_in[9];
    float* out = (float*)d_out;

    float* ws = (float*)d_ws;
    float* p1   = ws;                        // 1,048,576
    float* t2   = p1 + 1048576;              //   524,288
    float* t3   = t2 + 524288;               //   524,288
    float* t4   = t3 + 524288;               // 18,874,368 (channel-major)
    float* wdt2 = t4 + 18874368;             //    36,864 (k-major)

    k_wdt<<<144, 256, 0, stream>>>(wd, wdt2);
    k_conv0_pool<<<1024, 256, 0, stream>>>(x, w0, b0, p1);
    k_conv1x1_a<<<512, 256, 0, stream>>>(p1, w1, b1, t2);
    k_conv3x3_b<<<512, 256, 0, stream>>>(t2, w2, b2, t3);
    k_conv1x1_off<<<4608, 256, 0, stream>>>(t3, w3, b3, t4);
    k_deform<<<1024, 256, 0, stream>>>(x, t4, wdt2, out);
}